// Round 6
// baseline (73.844 us; speedup 1.0000x reference)
//
#include <hip/hip_runtime.h>

#define NROWS 8192
#define DIM   256          // elements per row == bytes per row in fp8
#define BHALF 4096
#define NCHUNK 8           // col chunks per 128-row panel (1024 cols each)
#define SCALE 1.69864358f  // sqrt(2 * log2(e)): dot = sim * log2(e)
#define LN2F  0.69314718f

typedef unsigned char u8;
typedef __attribute__((ext_vector_type(4))) float f32x4;
typedef __attribute__((ext_vector_type(4))) int   i32x4;
typedef __attribute__((ext_vector_type(8))) int   i32x8;

__device__ inline void gload_lds16(const void* g, void* l) {
  __builtin_amdgcn_global_load_lds(
      (const __attribute__((address_space(1))) void*)g,
      (__attribute__((address_space(3))) void*)l, 16, 0, 0);
}

// Kernel 1: row-normalize concat(z_i, z_j), scale by sqrt(2*log2e) so the fp8
// Gram dot = sim*log2e (exp2 instead of exp in the sum). Zeroes out scalar
// and the per-panel completion counters (stream-ordered before sim).
__global__ __launch_bounds__(256) void nrm_kernel(const float* __restrict__ zi,
                                                  const float* __restrict__ zj,
                                                  u8* __restrict__ zn8,
                                                  float* __restrict__ out,
                                                  int* __restrict__ cnt) {
  if (blockIdx.x == 0) {
    if (threadIdx.x == 0) out[0] = 0.f;
    if (threadIdx.x < 64) cnt[threadIdx.x] = 0;
  }
  const int w = threadIdx.x >> 6, l = threadIdx.x & 63;
  const int row = blockIdx.x * 4 + w;
  const float* src = (row < BHALF) ? zi + (size_t)row * DIM
                                   : zj + (size_t)(row - BHALF) * DIM;
  float4 v = *(const float4*)(src + l * 4);
  float ss = v.x * v.x + v.y * v.y + v.z * v.z + v.w * v.w;
#pragma unroll
  for (int m = 1; m < 64; m <<= 1) ss += __shfl_xor(ss, m);
  float inv = SCALE / fmaxf(sqrtf(ss), 1e-8f);
  int p = __builtin_amdgcn_cvt_pk_fp8_f32(v.x * inv, v.y * inv, 0, false);
  p = __builtin_amdgcn_cvt_pk_fp8_f32(v.z * inv, v.w * inv, p, true);
  *(int*)(zn8 + (size_t)row * DIM + (size_t)l * 4) = p;
}

// Kernel 2: full-matrix row-sum sweep + fused finish. Block = (panel rp,
// chunk ch). Panel -> registers (B-operand); 8 col-tiles stream through
// 2x32KB LDS, depth-1 prefetch, ONE barrier per tile, rolling per-ci
// pipeline (counted lgkmcnt, setprio'd MFMA cluster, exp2 overlapped).
// After stores, each block bumps cnt[rp] (fence+device atomic); the 8th
// arrival computes log(rowsum)-pos for its 128 rows and atomicAdds the loss.
__global__ __launch_bounds__(256, 2) void sim_kernel(const u8* __restrict__ zn8,
                                                     float* __restrict__ partials,
                                                     float* __restrict__ pos,
                                                     float* __restrict__ out,
                                                     int* __restrict__ cnt) {
  __shared__ __align__(16) u8 Bsm[2][128 * DIM];   // 2 x 32 KB
  __shared__ float plane[2][128];
  __shared__ int sfin;

  const int t = threadIdx.x;
  const int w = t >> 6, l = t & 63;
  const int wa = w >> 1, wb = w & 1;    // wa: col 64-half, wb: panel-row 64-half
  const int rl = l & 15, kg = l >> 4;   // kg = lane's 32B k-block

  const int rp = (int)blockIdx.x >> 3;  // row panel 0..63
  const int ch = (int)blockIdx.x & 7;   // col chunk 0..7
  const int colbase = ch * 1024;        // zn8 row index of first streamed tile

  // stage 128 rows x 256B; linear dest, source chunk inverse-swizzled (salt r&7)
  auto STAGE = [&](int base_row, u8* dst) {
#pragma unroll
    for (int i = 0; i < 8; ++i) {
      int c = i * 256 + t;              // 0..2047 16B-chunks
      int r = c >> 4, cd = c & 15;
      int cs = (cd & 8) | ((cd ^ r) & 7);
      gload_lds16(zn8 + (size_t)(base_row + r) * DIM + (size_t)cs * 16,
                  dst + (size_t)((i * 256 + w * 64) * 16));
    }
  };
  // swizzled fragment read: 32B of row `row`, both k-halves (4 ds_read_b128)
  auto RD2 = [&](const u8* buf, int row, i32x8* dst) {
    const int salt = row & 7;
    const u8* base = buf + row * DIM;
#pragma unroll
    for (int k = 0; k < 2; ++k) {
      i32x4 lo = *(const i32x4*)(base + ((k * 8 + ((kg * 2) ^ salt)) << 4));
      i32x4 hi = *(const i32x4*)(base + ((k * 8 + ((kg * 2 + 1) ^ salt)) << 4));
      dst[k] = __builtin_shufflevector(lo, hi, 0, 1, 2, 3, 4, 5, 6, 7);
    }
  };

  STAGE(rp * 128, &Bsm[0][0]);          // panel -> buf0 (8 loads)
  STAGE(colbase, &Bsm[1][0]);           // tile0 -> buf1 (8 more, 16 in flight)
  asm volatile("s_waitcnt vmcnt(8)" ::: "memory");   // panel landed
  __builtin_amdgcn_sched_barrier(0);
  __builtin_amdgcn_s_barrier();
  __builtin_amdgcn_sched_barrier(0);

  i32x8 pb[4][2];                       // panel fragments (B-operand), 64 VGPR
#pragma unroll
  for (int pj = 0; pj < 4; ++pj)
    RD2(&Bsm[0][0], wb * 64 + pj * 16 + rl, pb[pj]);
  asm volatile("s_waitcnt lgkmcnt(0)" ::: "memory");
  __builtin_amdgcn_sched_barrier(0);
  // no barrier here: tile0's barrier below also proves all waves finished pb

  const int dtile = ((rp >> 3) == ch) ? (rp & 7) : -1;      // diag tile (local)
  const int pg = (rp < 32) ? (rp + 32) : (rp - 32);         // pos col-panel
  const int ptile = ((pg >> 3) == ch) ? (pg & 7) : -1;      // pos tile (local)

  float rsum[4] = {0.f, 0.f, 0.f, 0.f};
  float pv[4]   = {0.f, 0.f, 0.f, 0.f};
  const bool dlane = (wa == wb) && (kg == (rl >> 2));       // self-pair lanes

#pragma unroll 2
  for (int ti = 0; ti < 8; ++ti) {
    asm volatile("s_waitcnt vmcnt(0)" ::: "memory");  // tile ti landed (my part)
    __builtin_amdgcn_sched_barrier(0);
    __builtin_amdgcn_s_barrier();       // all waves: ti ready AND ti-1 readers done
    __builtin_amdgcn_sched_barrier(0);

    const u8* Bb = &Bsm[(ti + 1) & 1][0];              // tile ti's buffer
    if (ti < 7) STAGE(colbase + (ti + 1) * 128, &Bsm[ti & 1][0]);  // depth-1

    const bool tdiag = (ti == dtile), tpos = (ti == ptile);

    i32x8 af[2][2];                     // rolling streamed fragments
    RD2(Bb, wa * 64 + rl, af[0]);       // ci=0 (4 ds_reads in flight)
#pragma unroll
    for (int ci = 0; ci < 4; ++ci) {
      if (ci < 3) RD2(Bb, wa * 64 + (ci + 1) * 16 + rl, af[(ci + 1) & 1]);
      if (ci < 3) asm volatile("s_waitcnt lgkmcnt(4)" ::: "memory");
      else        asm volatile("s_waitcnt lgkmcnt(0)" ::: "memory");
      __builtin_amdgcn_sched_barrier(0);

      f32x4 acc[4];
#pragma unroll
      for (int pj = 0; pj < 4; ++pj) acc[pj] = (f32x4){0.f, 0.f, 0.f, 0.f};
      __builtin_amdgcn_s_setprio(1);
#pragma unroll
      for (int k = 0; k < 2; ++k)
#pragma unroll
        for (int pj = 0; pj < 4; ++pj)
          acc[pj] = __builtin_amdgcn_mfma_scale_f32_16x16x128_f8f6f4(
              af[ci & 1][k], pb[pj][k], acc[pj],
              0, 0,                      // cbsz=fp8, blgp=fp8
              0, 0x7f7f7f7f,             // scale_a = 1.0 (e8m0 127)
              0, 0x7f7f7f7f);            // scale_b = 1.0
      __builtin_amdgcn_s_setprio(0);

      // epilogue for this ci: exp2 + lane-local row-sum (overlaps next MFMAs)
#pragma unroll
      for (int pj = 0; pj < 4; ++pj)
#pragma unroll
        for (int jj = 0; jj < 4; ++jj)
          rsum[pj] += __builtin_amdgcn_exp2f(acc[pj][jj]);
      if (tdiag && dlane)                // exact removal of the self term
        rsum[ci] -= __builtin_amdgcn_exp2f(acc[ci][rl & 3]);
      if (tpos && dlane) pv[ci] = acc[ci][rl & 3];
    }
  }

  // reduce rsum over the 4 kg lane-groups (bits 4..5), once per block
#pragma unroll
  for (int pj = 0; pj < 4; ++pj) {
    rsum[pj] += __shfl_xor(rsum[pj], 16);
    rsum[pj] += __shfl_xor(rsum[pj], 32);
  }
  if (kg == 0) {
#pragma unroll
    for (int pj = 0; pj < 4; ++pj)
      plane[wa][wb * 64 + pj * 16 + rl] = rsum[pj];
  }
  __syncthreads();
  if (t < 128)
    partials[(size_t)ch * NROWS + rp * 128 + t] = plane[0][t] + plane[1][t];
  if (ptile >= 0 && dlane) {
#pragma unroll
    for (int ci = 0; ci < 4; ++ci)
      pos[rp * 128 + wb * 64 + ci * 16 + rl] = pv[ci] * LN2F;  // back to nats
  }

  // ---- fused finish: 8th arrival for this panel folds log(sum)-pos ----
  __threadfence();                       // release my partials/pos stores
  __syncthreads();                       // all threads' fences done
  if (t == 0) {
    int old = atomicAdd(&cnt[rp], 1);    // device-scope RMW
    sfin = (old == 7) ? 1 : 0;
  }
  __syncthreads();
  if (sfin) {
    __threadfence();                     // acquire: see other blocks' stores
    float v = 0.f;
    if (t < 128) {
      const int r = rp * 128 + t;
      float s = 0.f;
#pragma unroll
      for (int c2 = 0; c2 < NCHUNK; ++c2) s += partials[(size_t)c2 * NROWS + r];
      v = logf(s) - pos[r];
    }
#pragma unroll
    for (int m = 1; m < 64; m <<= 1) v += __shfl_xor(v, m);
    __shared__ float wsum[2];
    if (l == 0 && t < 128) wsum[w] = v;
    __syncthreads();
    if (t == 0) atomicAdd(out, (wsum[0] + wsum[1]) * (1.f / NROWS));
  }
}

extern "C" void kernel_launch(void* const* d_in, const int* in_sizes, int n_in,
                              void* d_out, int out_size, void* d_ws, size_t ws_size,
                              hipStream_t stream) {
  const float* zi = (const float*)d_in[0];
  const float* zj = (const float*)d_in[1];

  u8*    zn8      = (u8*)d_ws;                                              // 2 MB
  float* partials = (float*)((char*)d_ws + (size_t)NROWS * DIM);            // 256 KB
  float* pos      = (float*)((char*)partials + (size_t)NCHUNK * NROWS * 4); // 32 KB
  int*   cnt      = (int*)((char*)pos + (size_t)NROWS * 4);                 // 256 B
  float* out      = (float*)d_out;

  nrm_kernel<<<NROWS / 4, 256, 0, stream>>>(zi, zj, zn8, out, cnt);
  sim_kernel<<<64 * NCHUNK, 256, 0, stream>>>(zn8, partials, pos, out, cnt);
}

// Round 7
// 38.213 us; speedup vs baseline: 1.9324x; 1.9324x over previous
//
#include <hip/hip_runtime.h>

#define NROWS 8192
#define DIM   256          // elements per row == bytes per row in fp8
#define BHALF 4096
#define NCHUNK 16          // col chunks per 128-row panel (512 cols each)
#define SCALE 1.69864358f  // sqrt(2 * log2(e)): dot = sim * log2(e)
#define LN2F  0.69314718f

typedef unsigned char u8;
typedef __attribute__((ext_vector_type(4))) float f32x4;
typedef __attribute__((ext_vector_type(4))) int   i32x4;
typedef __attribute__((ext_vector_type(8))) int   i32x8;

__device__ inline void gload_lds16(const void* g, void* l) {
  __builtin_amdgcn_global_load_lds(
      (const __attribute__((address_space(1))) void*)g,
      (__attribute__((address_space(3))) void*)l, 16, 0, 0);
}

// Kernel 1: row-normalize concat(z_i, z_j), scale by sqrt(2*log2e) so the fp8
// Gram dot = sim*log2e (exp2 instead of exp in the sum). Zeroes out scalar.
__global__ __launch_bounds__(256) void nrm_kernel(const float* __restrict__ zi,
                                                  const float* __restrict__ zj,
                                                  u8* __restrict__ zn8,
                                                  float* __restrict__ out) {
  if (blockIdx.x == 0 && threadIdx.x == 0) out[0] = 0.f;
  const int w = threadIdx.x >> 6, l = threadIdx.x & 63;
  const int row = blockIdx.x * 4 + w;
  const float* src = (row < BHALF) ? zi + (size_t)row * DIM
                                   : zj + (size_t)(row - BHALF) * DIM;
  float4 v = *(const float4*)(src + l * 4);
  float ss = v.x * v.x + v.y * v.y + v.z * v.z + v.w * v.w;
#pragma unroll
  for (int m = 1; m < 64; m <<= 1) ss += __shfl_xor(ss, m);
  float inv = SCALE / fmaxf(sqrtf(ss), 1e-8f);
  int p = __builtin_amdgcn_cvt_pk_fp8_f32(v.x * inv, v.y * inv, 0, false);
  p = __builtin_amdgcn_cvt_pk_fp8_f32(v.z * inv, v.w * inv, p, true);
  *(int*)(zn8 + (size_t)row * DIM + (size_t)l * 4) = p;
}

// Kernel 2: full-matrix row-sum sweep. Block = (panel rp, chunk ch):
// 128 panel rows x 512 cols. Panel (32KB) staged across both buffers ->
// registers; then 8 col-tiles of 64 cols stream through 2x16KB LDS,
// depth-1 prefetch, ONE barrier per tile. 33.5KB LDS + VGPR<=128 ->
// 4 independent blocks/CU: MFMA and exp2 bursts from different blocks
// anti-phase on each SIMD (the r5 2-block lockstep made them additive).
__global__ __launch_bounds__(256, 4) void sim_kernel(const u8* __restrict__ zn8,
                                                     float* __restrict__ partials,
                                                     float* __restrict__ pos) {
  __shared__ __align__(16) u8 Bsm[2][64 * DIM];    // 2 x 16 KB (panel uses both)
  __shared__ float plane[2][128];

  const int t = threadIdx.x;
  const int w = t >> 6, l = t & 63;
  const int wa = w >> 1, wb = w & 1;    // wa: col 32-half, wb: panel-row 64-half
  const int rl = l & 15, kg = l >> 4;   // kg = lane's 32B k-block

  const int rp = (int)blockIdx.x >> 4;  // row panel 0..63
  const int ch = (int)blockIdx.x & 15;  // col chunk 0..15
  const int colbase = ch * 512;         // zn8 row index of first streamed tile

  // stage 128 rows x 256B (panel) across both buffers
  auto STAGE_P = [&](int base_row, u8* dst) {
#pragma unroll
    for (int i = 0; i < 8; ++i) {
      int c = i * 256 + t;              // 0..2047 16B-chunks
      int r = c >> 4, cd = c & 15;
      int cs = (cd & 8) | ((cd ^ r) & 7);
      gload_lds16(zn8 + (size_t)(base_row + r) * DIM + (size_t)cs * 16,
                  dst + (size_t)((i * 256 + w * 64) * 16));
    }
  };
  // stage 64 rows x 256B (one col tile) into one 16KB buffer
  auto STAGE_T = [&](int base_row, u8* dst) {
#pragma unroll
    for (int i = 0; i < 4; ++i) {
      int c = i * 256 + t;              // 0..1023 16B-chunks
      int r = c >> 4, cd = c & 15;
      int cs = (cd & 8) | ((cd ^ r) & 7);
      gload_lds16(zn8 + (size_t)(base_row + r) * DIM + (size_t)cs * 16,
                  dst + (size_t)((i * 256 + w * 64) * 16));
    }
  };
  // swizzled fragment read: 32B of row `row`, both k-halves (4 ds_read_b128)
  auto RD2 = [&](const u8* buf, int row, i32x8* dst) {
    const int salt = row & 7;
    const u8* base = buf + row * DIM;
#pragma unroll
    for (int k = 0; k < 2; ++k) {
      i32x4 lo = *(const i32x4*)(base + ((k * 8 + ((kg * 2) ^ salt)) << 4));
      i32x4 hi = *(const i32x4*)(base + ((k * 8 + ((kg * 2 + 1) ^ salt)) << 4));
      dst[k] = __builtin_shufflevector(lo, hi, 0, 1, 2, 3, 4, 5, 6, 7);
    }
  };

  STAGE_P(rp * 128, &Bsm[0][0]);        // panel -> both buffers (8 loads)
  asm volatile("s_waitcnt vmcnt(0)" ::: "memory");
  __builtin_amdgcn_sched_barrier(0);
  __builtin_amdgcn_s_barrier();
  __builtin_amdgcn_sched_barrier(0);

  i32x8 pb[4][2];                       // panel fragments (B-operand), 64 VGPR
#pragma unroll
  for (int pj = 0; pj < 4; ++pj)
    RD2(&Bsm[0][0], wb * 64 + pj * 16 + rl, pb[pj]);
  asm volatile("s_waitcnt lgkmcnt(0)" ::: "memory");
  __builtin_amdgcn_sched_barrier(0);
  __builtin_amdgcn_s_barrier();         // panel region free for tile staging
  __builtin_amdgcn_sched_barrier(0);
  STAGE_T(colbase, &Bsm[1][0]);         // tile0 -> buf1 (4 loads)

  // per-wave diagonal / positive 64-col tile indices (local to this chunk)
  const int dg  = rp * 2 + wb;                       // my rows' global 64-tile
  const int ptg = dg + ((rp < 32) ? 64 : -64);       // positive-pair col tile
  const int dt = ((dg >> 3) == ch)  ? (dg & 7)  : -1;
  const int pt = ((ptg >> 3) == ch) ? (ptg & 7) : -1;
  const bool dlane = (kg == (rl >> 2));              // tile-diag lanes

  float rsum[4] = {0.f, 0.f, 0.f, 0.f};
  float pv[2]   = {0.f, 0.f};

#pragma unroll 2
  for (int ti = 0; ti < 8; ++ti) {
    asm volatile("s_waitcnt vmcnt(0)" ::: "memory"); // tile ti landed (my part)
    __builtin_amdgcn_sched_barrier(0);
    __builtin_amdgcn_s_barrier();       // all waves: ti ready AND ti-1 readers done
    __builtin_amdgcn_sched_barrier(0);

    const u8* Bb = &Bsm[(ti + 1) & 1][0];            // tile ti's buffer
    if (ti < 7) STAGE_T(colbase + (ti + 1) * 64, &Bsm[ti & 1][0]);  // depth-1

    const bool tdiag = (ti == dt), tpos = (ti == pt);

#pragma unroll
    for (int ci = 0; ci < 2; ++ci) {
      i32x8 af[2];
      RD2(Bb, wa * 32 + ci * 16 + rl, af);
      asm volatile("s_waitcnt lgkmcnt(0)" ::: "memory");
      __builtin_amdgcn_sched_barrier(0);

      f32x4 acc[4];
#pragma unroll
      for (int pj = 0; pj < 4; ++pj) acc[pj] = (f32x4){0.f, 0.f, 0.f, 0.f};
      __builtin_amdgcn_s_setprio(1);
#pragma unroll
      for (int k = 0; k < 2; ++k)
#pragma unroll
        for (int pj = 0; pj < 4; ++pj)
          acc[pj] = __builtin_amdgcn_mfma_scale_f32_16x16x128_f8f6f4(
              af[k], pb[pj][k], acc[pj],
              0, 0,                      // cbsz=fp8, blgp=fp8
              0, 0x7f7f7f7f,             // scale_a = 1.0 (e8m0 127)
              0, 0x7f7f7f7f);            // scale_b = 1.0
      __builtin_amdgcn_s_setprio(0);

      // exp2 + lane-local row-sum (overlaps other blocks' MFMA bursts)
#pragma unroll
      for (int pj = 0; pj < 4; ++pj)
#pragma unroll
        for (int jj = 0; jj < 4; ++jj)
          rsum[pj] += __builtin_amdgcn_exp2f(acc[pj][jj]);
      const int pjs = wa * 2 + ci;       // tile index matching my cols
      if (tdiag && dlane)                // exact removal of the self term
        rsum[pjs] -= __builtin_amdgcn_exp2f(acc[pjs][rl & 3]);
      if (tpos && dlane) pv[ci] = acc[pjs][rl & 3];
    }
  }

  // reduce rsum over the 4 kg lane-groups (bits 4..5), once per block
#pragma unroll
  for (int pj = 0; pj < 4; ++pj) {
    rsum[pj] += __shfl_xor(rsum[pj], 16);
    rsum[pj] += __shfl_xor(rsum[pj], 32);
  }
  if (kg == 0) {
#pragma unroll
    for (int pj = 0; pj < 4; ++pj)
      plane[wa][wb * 64 + pj * 16 + rl] = rsum[pj];
  }
  __syncthreads();
  if (t < 128)
    partials[(size_t)ch * NROWS + rp * 128 + t] = plane[0][t] + plane[1][t];
  if (pt >= 0 && dlane) {
#pragma unroll
    for (int ci = 0; ci < 2; ++ci)
      pos[rp * 128 + wb * 64 + (wa * 2 + ci) * 16 + rl] = pv[ci] * LN2F;
  }
}

// Kernel 3: per-row lse - pos; block sums folded into one global atomic
// (out pre-zeroed by nrm_kernel; stream order guarantees visibility).
__global__ __launch_bounds__(256) void fin_kernel(const float* __restrict__ partials,
                                                  const float* __restrict__ pos,
                                                  float* __restrict__ out) {
  const int r = blockIdx.x * 256 + threadIdx.x;
  float s = 0.f;
#pragma unroll
  for (int ch = 0; ch < NCHUNK; ++ch) s += partials[(size_t)ch * NROWS + r];
  float v = logf(s) - pos[r];
#pragma unroll
  for (int m = 1; m < 64; m <<= 1) v += __shfl_xor(v, m);
  __shared__ float wsum[4];
  const int w = threadIdx.x >> 6, l = threadIdx.x & 63;
  if (l == 0) wsum[w] = v;
  __syncthreads();
  if (threadIdx.x == 0)
    atomicAdd(out, (wsum[0] + wsum[1] + wsum[2] + wsum[3]) * (1.f / NROWS));
}

extern "C" void kernel_launch(void* const* d_in, const int* in_sizes, int n_in,
                              void* d_out, int out_size, void* d_ws, size_t ws_size,
                              hipStream_t stream) {
  const float* zi = (const float*)d_in[0];
  const float* zj = (const float*)d_in[1];

  u8*    zn8      = (u8*)d_ws;                                              // 2 MB
  float* partials = (float*)((char*)d_ws + (size_t)NROWS * DIM);            // 512 KB
  float* pos      = (float*)((char*)partials + (size_t)NCHUNK * NROWS * 4); // 32 KB
  float* out      = (float*)d_out;

  nrm_kernel<<<NROWS / 4, 256, 0, stream>>>(zi, zj, zn8, out);
  sim_kernel<<<64 * NCHUNK, 256, 0, stream>>>(zn8, partials, pos);
  fin_kernel<<<NROWS / 256, 256, 0, stream>>>(partials, pos, out);
}

// Round 8
// 34.414 us; speedup vs baseline: 2.1457x; 1.1104x over previous
//
#include <hip/hip_runtime.h>

#define NROWS 8192
#define DIM   256          // elements per row == bytes per row in fp8
#define BHALF 4096
#define NCHUNK 8           // col chunks per 128-row panel (1024 cols each)
#define SCALE 1.69864358f  // sqrt(2 * log2(e)): dot = sim * log2(e)
#define LN2F  0.69314718f

typedef unsigned char u8;
typedef __attribute__((ext_vector_type(16))) float f32x16;
typedef __attribute__((ext_vector_type(4))) int   i32x4;
typedef __attribute__((ext_vector_type(8))) int   i32x8;

__device__ inline void gload_lds16(const void* g, void* l) {
  __builtin_amdgcn_global_load_lds(
      (const __attribute__((address_space(1))) void*)g,
      (__attribute__((address_space(3))) void*)l, 16, 0, 0);
}

// Kernel 1: row-normalize concat(z_i, z_j), scale by sqrt(2*log2e) so the fp8
// Gram dot = sim*log2e (exp2 instead of exp in the sum). Zeroes out scalar.
__global__ __launch_bounds__(256) void nrm_kernel(const float* __restrict__ zi,
                                                  const float* __restrict__ zj,
                                                  u8* __restrict__ zn8,
                                                  float* __restrict__ out) {
  if (blockIdx.x == 0 && threadIdx.x == 0) out[0] = 0.f;
  const int w = threadIdx.x >> 6, l = threadIdx.x & 63;
  const int row = blockIdx.x * 4 + w;
  const float* src = (row < BHALF) ? zi + (size_t)row * DIM
                                   : zj + (size_t)(row - BHALF) * DIM;
  float4 v = *(const float4*)(src + l * 4);
  float ss = v.x * v.x + v.y * v.y + v.z * v.z + v.w * v.w;
#pragma unroll
  for (int m = 1; m < 64; m <<= 1) ss += __shfl_xor(ss, m);
  float inv = SCALE / fmaxf(sqrtf(ss), 1e-8f);
  int p = __builtin_amdgcn_cvt_pk_fp8_f32(v.x * inv, v.y * inv, 0, false);
  p = __builtin_amdgcn_cvt_pk_fp8_f32(v.z * inv, v.w * inv, p, true);
  *(int*)(zn8 + (size_t)row * DIM + (size_t)l * 4) = p;
}

// Kernel 2: full-matrix row-sum sweep, 32x32x64 MX-fp8 MFMA (2x the FLOP/cyc
// of 16x16x128). Block = (panel rp, chunk ch): 128 panel rows x 1024 cols,
// r5 skeleton: panel -> registers (B-operand, pb[4][4] = 128 VGPR); 8
// col-tiles of 128 stream through 2x32KB LDS, depth-1 prefetch, ONE barrier
// per tile. Wave w owns col strip w*32; per tile: 4 kk x 4 pj MFMA with
// af double-buffered (counted lgkmcnt), setprio'd clusters, exp2 after.
__global__ __launch_bounds__(256, 2) void sim_kernel(const u8* __restrict__ zn8,
                                                     float* __restrict__ partials,
                                                     float* __restrict__ pos) {
  __shared__ __align__(16) u8 Bsm[2][128 * DIM];   // 2 x 32 KB
  __shared__ float plane[4][128];

  const int t = threadIdx.x;
  const int w = t >> 6, l = t & 63;     // w = col strip (32 cols)
  const int n31 = l & 31, kh = l >> 5;  // output col / operand k-half

  const int rp = (int)blockIdx.x >> 3;  // row panel 0..63
  const int ch = (int)blockIdx.x & 7;   // col chunk 0..7
  const int colbase = ch * 1024;        // zn8 row index of first streamed tile

  // stage 128 rows x 256B; linear dest, source chunk inverse-swizzled (salt r&7)
  auto STAGE = [&](int base_row, u8* dst) {
#pragma unroll
    for (int i = 0; i < 8; ++i) {
      int c = i * 256 + t;              // 0..2047 16B-chunks
      int r = c >> 4, cd = c & 15;
      int cs = (cd & 8) | ((cd ^ r) & 7);
      gload_lds16(zn8 + (size_t)(base_row + r) * DIM + (size_t)cs * 16,
                  dst + (size_t)((i * 256 + w * 64) * 16));
    }
  };
  // swizzled fragment read for 32x32x64: 32B of row `row`, k-step kk (0..3).
  // logical chunks c0,c0+1 with c0 = kk*4 + kh*2; phys = (c&8)|((c^salt)&7).
  auto RD32 = [&](const u8* buf, int row, int kk) -> i32x8 {
    const int salt = row & 7;
    const u8* base = buf + row * DIM;
    const int c0 = kk * 4 + kh * 2;
    i32x4 lo = *(const i32x4*)(base + (((c0 & 8) | ((c0 ^ salt) & 7)) << 4));
    i32x4 hi = *(const i32x4*)(base + ((((c0 + 1) & 8) | (((c0 + 1) ^ salt) & 7)) << 4));
    return __builtin_shufflevector(lo, hi, 0, 1, 2, 3, 4, 5, 6, 7);
  };

  STAGE(rp * 128, &Bsm[0][0]);          // panel -> buf0 (8 loads)
  STAGE(colbase, &Bsm[1][0]);           // tile0 -> buf1 (8 more, 16 in flight)
  asm volatile("s_waitcnt vmcnt(8)" ::: "memory");   // panel landed
  __builtin_amdgcn_sched_barrier(0);
  __builtin_amdgcn_s_barrier();
  __builtin_amdgcn_sched_barrier(0);

  i32x8 pb[4][4];                       // panel B-frags [pj][kk], 128 VGPR
#pragma unroll
  for (int pj = 0; pj < 4; ++pj)
#pragma unroll
    for (int kk = 0; kk < 4; ++kk)
      pb[pj][kk] = RD32(&Bsm[0][0], pj * 32 + n31, kk);
  asm volatile("s_waitcnt lgkmcnt(0)" ::: "memory");
  __builtin_amdgcn_sched_barrier(0);
  // no barrier here: tile0's barrier below also proves all waves finished pb

  const int dt = ((rp >> 3) == ch) ? (rp & 7) : -1;         // diag tile (local)
  const int pg = (rp < 32) ? (rp + 32) : (rp - 32);         // pos col-panel
  const int pt = ((pg >> 3) == ch) ? (pg & 7) : -1;         // pos tile (local)
  // self/pos element exists in this lane iff bit2(n31) == kh; then reg index:
  const bool dsel = (((l >> 2) & 1) == kh);
  const int regsel = (l & 3) | (((l >> 3) & 3) << 2);

  float rsum[4] = {0.f, 0.f, 0.f, 0.f};
  float pv = 0.f;

  for (int ti = 0; ti < 8; ++ti) {
    asm volatile("s_waitcnt vmcnt(0)" ::: "memory"); // tile ti landed (my part)
    __builtin_amdgcn_sched_barrier(0);
    __builtin_amdgcn_s_barrier();       // all waves: ti ready AND ti-1 readers done
    __builtin_amdgcn_sched_barrier(0);

    const u8* Bb = &Bsm[(ti + 1) & 1][0];            // tile ti's buffer
    if (ti < 7) STAGE(colbase + (ti + 1) * 128, &Bsm[ti & 1][0]);  // depth-1

    f32x16 acc[4];
#pragma unroll
    for (int pj = 0; pj < 4; ++pj) acc[pj] = (f32x16)(0.f);

    i32x8 af0 = RD32(Bb, w * 32 + n31, 0);
    i32x8 af1;
#pragma unroll
    for (int kk = 0; kk < 4; ++kk) {
      if (kk < 3) {
        i32x8 nxt = RD32(Bb, w * 32 + n31, kk + 1);
        if (kk & 1) af0 = nxt; else af1 = nxt;
        asm volatile("s_waitcnt lgkmcnt(2)" ::: "memory");
      } else {
        asm volatile("s_waitcnt lgkmcnt(0)" ::: "memory");
      }
      __builtin_amdgcn_sched_barrier(0);
      const i32x8 a = (kk & 1) ? af1 : af0;
      __builtin_amdgcn_s_setprio(1);
#pragma unroll
      for (int pj = 0; pj < 4; ++pj)
        acc[pj] = __builtin_amdgcn_mfma_scale_f32_32x32x64_f8f6f4(
            a, pb[pj][kk], acc[pj],
            0, 0,                        // cbsz=fp8, blgp=fp8
            0, 0x7f7f7f7f,               // scale_a = 1.0 (e8m0 127)
            0, 0x7f7f7f7f);              // scale_b = 1.0
      __builtin_amdgcn_s_setprio(0);
    }

    // epilogue: exp2 + lane-local row-sum (tree per pj to shorten dep chains)
#pragma unroll
    for (int pj = 0; pj < 4; ++pj) {
      float e0 = 0.f, e1 = 0.f, e2 = 0.f, e3 = 0.f;
#pragma unroll
      for (int r16 = 0; r16 < 16; r16 += 4) {
        e0 += __builtin_amdgcn_exp2f(acc[pj][r16]);
        e1 += __builtin_amdgcn_exp2f(acc[pj][r16 + 1]);
        e2 += __builtin_amdgcn_exp2f(acc[pj][r16 + 2]);
        e3 += __builtin_amdgcn_exp2f(acc[pj][r16 + 3]);
      }
      rsum[pj] += (e0 + e1) + (e2 + e3);
    }
    if (ti == dt && dsel) {              // exact removal of the self term
#pragma unroll
      for (int pj = 0; pj < 4; ++pj)
        if (pj == w) {
          float sv = acc[pj][0];
#pragma unroll
          for (int r16 = 1; r16 < 16; ++r16)
            sv = (regsel == r16) ? acc[pj][r16] : sv;
          rsum[pj] -= __builtin_amdgcn_exp2f(sv);
        }
    }
    if (ti == pt && dsel) {              // positive-pair extraction
#pragma unroll
      for (int pj = 0; pj < 4; ++pj)
        if (pj == w) {
          float sv = acc[pj][0];
#pragma unroll
          for (int r16 = 1; r16 < 16; ++r16)
            sv = (regsel == r16) ? acc[pj][r16] : sv;
          pv = sv;
        }
    }
  }

  // each panel row lives in 2 lanes (l, l^32): one xor, then 4-wave plane sum
#pragma unroll
  for (int pj = 0; pj < 4; ++pj) {
    rsum[pj] += __shfl_xor(rsum[pj], 32);
    if (l < 32) plane[w][pj * 32 + l] = rsum[pj];
  }
  __syncthreads();
  if (t < 128)
    partials[(size_t)ch * NROWS + rp * 128 + t] =
        (plane[0][t] + plane[1][t]) + (plane[2][t] + plane[3][t]);
  if (pt >= 0 && dsel)
    pos[rp * 128 + w * 32 + n31] = pv * LN2F;      // back to nats
}

// Kernel 3: per-row lse - pos; block sums folded into one global atomic
// (out pre-zeroed by nrm_kernel; stream order guarantees visibility).
__global__ __launch_bounds__(256) void fin_kernel(const float* __restrict__ partials,
                                                  const float* __restrict__ pos,
                                                  float* __restrict__ out) {
  const int r = blockIdx.x * 256 + threadIdx.x;
  float s = 0.f;
#pragma unroll
  for (int ch = 0; ch < NCHUNK; ++ch) s += partials[(size_t)ch * NROWS + r];
  float v = logf(s) - pos[r];
#pragma unroll
  for (int m = 1; m < 64; m <<= 1) v += __shfl_xor(v, m);
  __shared__ float wsum[4];
  const int w = threadIdx.x >> 6, l = threadIdx.x & 63;
  if (l == 0) wsum[w] = v;
  __syncthreads();
  if (threadIdx.x == 0)
    atomicAdd(out, (wsum[0] + wsum[1] + wsum[2] + wsum[3]) * (1.f / NROWS));
}

extern "C" void kernel_launch(void* const* d_in, const int* in_sizes, int n_in,
                              void* d_out, int out_size, void* d_ws, size_t ws_size,
                              hipStream_t stream) {
  const float* zi = (const float*)d_in[0];
  const float* zj = (const float*)d_in[1];

  u8*    zn8      = (u8*)d_ws;                                              // 2 MB
  float* partials = (float*)((char*)d_ws + (size_t)NROWS * DIM);            // 256 KB
  float* pos      = (float*)((char*)partials + (size_t)NCHUNK * NROWS * 4); // 32 KB
  float* out      = (float*)d_out;

  nrm_kernel<<<NROWS / 4, 256, 0, stream>>>(zi, zj, zn8, out);
  sim_kernel<<<64 * NCHUNK, 256, 0, stream>>>(zn8, partials, pos);
  fin_kernel<<<NROWS / 256, 256, 0, stream>>>(partials, pos, out);
}